// Round 15
// baseline (3252.525 us; speedup 1.0000x reference)
//
#include <hip/hip_runtime.h>
#include <hip/hip_bf16.h>

#define B_ 256
#define T_ 512
#define F_ 8
#define H_ 512
#define OUT_ 96

// 16 batch-clusters x (8 workgroups x 4 waves). Each wave owns 16 h-cols
// (48 gate-cols), W slice register-resident. 128 blocks of 256 thr =>
// co-residency guaranteed by capacity. Round-8 protocol (best: 1722us) with
// ONE change: gather uses PLAIN coalescing dwordx4 loads guarded by an
// acquire fence (atomic per-lane loads don't coalesce -> were the hidden
// ~5kcy/step). Publish stays agent-scope atomic stores (write through to L3).
#define NCL 16
#define BT 16
#define NWG 8

typedef __attribute__((ext_vector_type(8))) short short8;
typedef __attribute__((ext_vector_type(4))) float f32x4;

// g_hbuf: [buf][chunk=col>>3][row][2 u64]  (16B = 8 bf16 cols per (chunk,row))
__device__ unsigned long long g_hbuf[2ull * 64 * 256 * 2];
// per-cluster flag block: 8 u32 packed in ONE 64B line (single-request poll)
__device__ __align__(64) unsigned g_flag[NCL * 16];

__device__ __forceinline__ short f2bf(float v) {
  __hip_bfloat16 b = __float2bfloat16(v);
  unsigned short u;
  __builtin_memcpy(&u, &b, 2);
  return (short)u;
}

__device__ __forceinline__ size_t hidx(int buf, int chunk, int row) {
  return ((size_t)((buf * 64 + chunk) * 256 + row)) * 2;
}

__global__ void init_flags() {
  int i = blockIdx.x * 256 + (int)threadIdx.x;
  if (i < NCL * 16) g_flag[i] = 0;
}

__global__ __launch_bounds__(256, 1) void gru_persistent(
    const float* x, const float* w_ih, const float* w_hh,
    const float* bias_ih, const float* bias_hh,
    const float* fc_w, const float* fc_b, float* out) {
  const int tid = (int)threadIdx.x;
  const int w = tid >> 6;
  const int lane = tid & 63;
  const int l15 = lane & 15;
  const int lg = lane >> 4;
  const int bid = (int)blockIdx.x;
  const int cl = bid & 15;   // cluster
  const int wgj = bid >> 4;  // wg within cluster
  const int rb0 = cl * BT;
  const int c0 = wgj * 64 + w * 16;

  __shared__ short8 h_lds[1024];   // [chunk*16 + localrow], lane-linear (16 KB)
  __shared__ short t_h[16][68];    // publish transpose tile, padded stride

  // ---- W fragments, register-resident for all 512 steps ----
  short8 wfrag[3][17];
#pragma unroll
  for (int g = 0; g < 3; ++g) {
    const float* wr = w_hh + (size_t)(g * H_ + c0 + l15) * H_ + lg * 8;
#pragma unroll
    for (int kk = 0; kk < 16; ++kk) {
      f32x4 a = ((const f32x4*)(wr + kk * 32))[0];
      f32x4 b2 = ((const f32x4*)(wr + kk * 32))[1];
      short8 o;
#pragma unroll
      for (int j = 0; j < 4; ++j) { o[j] = f2bf(a[j]); o[4 + j] = f2bf(b2[j]); }
      wfrag[g][kk] = o;
    }
    short8 o = {0, 0, 0, 0, 0, 0, 0, 0};
    if (lg == 0) {  // k = 512..519 -> W_ih row
      const f32x4* wi = (const f32x4*)(w_ih + (size_t)(g * H_ + c0 + l15) * F_);
      f32x4 a = wi[0], b2 = wi[1];
#pragma unroll
      for (int j = 0; j < 4; ++j) { o[j] = f2bf(a[j]); o[4 + j] = f2bf(b2[j]); }
    }
    wfrag[g][16] = o;
  }

  const int colh = c0 + l15;
  const float b_r = bias_ih[colh] + bias_hh[colh];
  const float b_z = bias_ih[H_ + colh] + bias_hh[H_ + colh];
  const float bin_ = bias_ih[2 * H_ + colh];
  const float bhn_ = bias_hh[2 * H_ + colh];

  float hown[4] = {0.f, 0.f, 0.f, 0.f};
  bool gaveup = false;

  const int hrow = rb0 + l15;
  const float* xrow = x + (size_t)hrow * T_ * F_;

  // x prefetch for t=0
  f32x4 xa = ((const f32x4*)xrow)[0];
  f32x4 xb2 = ((const f32x4*)xrow)[1];

  for (int t = 0; t < T_; ++t) {
    if (t > 0) {
      // ---- poll: ONE coalesced load per wave per iteration, __all exit ----
      if (!gaveup) {
        unsigned spins = 0;
        for (;;) {
          unsigned f = __hip_atomic_load(&g_flag[cl * 16 + (lane & 7)],
                                         __ATOMIC_RELAXED, __HIP_MEMORY_SCOPE_AGENT);
          if (__all((int)(f >= (unsigned)t))) break;
          __builtin_amdgcn_s_sleep(2);
          if (++spins > (1u << 20)) { gaveup = true; break; }
        }
        // Acquire fence: invalidate L1/L2 so the PLAIN coalescing loads below
        // observe the producers' L3-visible atomic stores. x/W/biases are all
        // register-resident, so the L2 nuke costs ~nothing now.
        __builtin_amdgcn_fence(__ATOMIC_ACQUIRE, "agent");
      }
      // ---- cooperative gather: plain dwordx4 loads (coalesced), lane-linear ----
      const int buf = t & 1;
#pragma unroll
      for (int r4 = 0; r4 < 4; ++r4) {
        const int idx = r4 * 256 + tid;     // 0..1023
        size_t i0 = hidx(buf, idx >> 4, rb0 + (idx & 15));
        h_lds[idx] = *(const short8*)&g_hbuf[i0];
      }
    }

    // x fragment from prefetched registers
    short8 xf;
#pragma unroll
    for (int j = 0; j < 4; ++j) { xf[j] = f2bf(xa[j]); xf[4 + j] = f2bf(xb2[j]); }

    __syncthreads();  // h_lds ready

    // prefetch x for t+1 (register-resident across the next fence)
    {
      const int tn = (t + 1 < T_) ? t + 1 : T_ - 1;
      xa = ((const f32x4*)(xrow + (size_t)tn * F_))[0];
      xb2 = ((const f32x4*)(xrow + (size_t)tn * F_))[1];
    }

    // ---- MFMAs: 3 gates per kk ----
    f32x4 acc_r = {0.f, 0.f, 0.f, 0.f}, acc_z = {0.f, 0.f, 0.f, 0.f};
    f32x4 acc_nh = {0.f, 0.f, 0.f, 0.f}, acc_nx = {0.f, 0.f, 0.f, 0.f};
    if (t > 0) {
#pragma unroll
      for (int kk = 0; kk < 16; ++kk) {
        short8 a = h_lds[(kk * 4 + lg) * 16 + l15];
        acc_r = __builtin_amdgcn_mfma_f32_16x16x32_bf16(a, wfrag[0][kk], acc_r, 0, 0, 0);
        acc_z = __builtin_amdgcn_mfma_f32_16x16x32_bf16(a, wfrag[1][kk], acc_z, 0, 0, 0);
        acc_nh = __builtin_amdgcn_mfma_f32_16x16x32_bf16(a, wfrag[2][kk], acc_nh, 0, 0, 0);
      }
    }
    acc_r = __builtin_amdgcn_mfma_f32_16x16x32_bf16(xf, wfrag[0][16], acc_r, 0, 0, 0);
    acc_z = __builtin_amdgcn_mfma_f32_16x16x32_bf16(xf, wfrag[1][16], acc_z, 0, 0, 0);
    acc_nx = __builtin_amdgcn_mfma_f32_16x16x32_bf16(xf, wfrag[2][16], acc_nx, 0, 0, 0);

    // ---- gates + fp32-carry state update ----
    short hnew[4];
#pragma unroll
    for (int q = 0; q < 4; ++q) {
      float pr = acc_r[q] + b_r;
      float pz = acc_z[q] + b_z;
      float r = 1.f / (1.f + __expf(-pr));
      float z = 1.f / (1.f + __expf(-pz));
      float n = tanhf(acc_nx[q] + bin_ + r * (acc_nh[q] + bhn_));
      hown[q] = n + z * (hown[q] - n);
      hnew[q] = f2bf(hown[q]);
    }

    // ---- publish via padded LDS transpose -> one aligned u64 atomic store/lane ----
#pragma unroll
    for (int q = 0; q < 4; ++q) t_h[4 * lg + q][w * 16 + l15] = hnew[q];
    __syncthreads();  // tile complete
    {
      const int row_l = tid >> 4;
      const int ucol = tid & 15;
      const int col = wgj * 64 + ucol * 4;
      const int grow = rb0 + row_l;
      unsigned long long v;
      __builtin_memcpy(&v, &t_h[row_l][ucol * 4], 8);
      size_t i0 = hidx((t + 1) & 1, col >> 3, grow) + ((col >> 2) & 1);
      __hip_atomic_store(&g_hbuf[i0], v, __ATOMIC_RELAXED, __HIP_MEMORY_SCOPE_AGENT);
    }
    __syncthreads();  // vmcnt(0) drain: all 4 waves' stores at coherence point
    if (tid == 0)     // release: relaxed store into the packed cluster line
      __hip_atomic_store(&g_flag[cl * 16 + wgj], (unsigned)(t + 1),
                         __ATOMIC_RELAXED, __HIP_MEMORY_SCOPE_AGENT);
  }

  // ---- final FC: 6 waves per cluster cover the 96 output columns ----
  const int wi = wgj * 4 + w;
  if (wi >= OUT_ / 16) return;
  if (!gaveup) {
    unsigned spins = 0;
    for (;;) {
      unsigned f = __hip_atomic_load(&g_flag[cl * 16 + (lane & 7)],
                                     __ATOMIC_RELAXED, __HIP_MEMORY_SCOPE_AGENT);
      if (__all((int)(f >= (unsigned)T_))) break;
      __builtin_amdgcn_s_sleep(2);
      if (++spins > (1u << 20)) break;
    }
    __builtin_amdgcn_fence(__ATOMIC_ACQUIRE, "agent");
  }
  short8 afrag[16];
#pragma unroll
  for (int kk = 0; kk < 16; ++kk) {  // h_512 is in buffer (512 & 1) == 0; plain loads
    size_t i0 = hidx(0, kk * 4 + lg, hrow);
    afrag[kk] = *(const short8*)&g_hbuf[i0];
  }
  const int col = wi * 16 + l15;
  const float* wrow = fc_w + (size_t)col * H_ + lg * 8;
  f32x4 acc = {0.f, 0.f, 0.f, 0.f};
#pragma unroll
  for (int kk = 0; kk < 16; ++kk) {
    f32x4 a = ((const f32x4*)(wrow + kk * 32))[0];
    f32x4 b2 = ((const f32x4*)(wrow + kk * 32))[1];
    short8 bfr;
#pragma unroll
    for (int j = 0; j < 4; ++j) { bfr[j] = f2bf(a[j]); bfr[4 + j] = f2bf(b2[j]); }
    acc = __builtin_amdgcn_mfma_f32_16x16x32_bf16(afrag[kk], bfr, acc, 0, 0, 0);
  }
  const float fb = fc_b[col];
#pragma unroll
  for (int q = 0; q < 4; ++q) {
    int row_o = rb0 + lg * 4 + q;
    out[(size_t)row_o * OUT_ + col] = acc[q] + fb;
  }
}

extern "C" void kernel_launch(void* const* d_in, const int* in_sizes, int n_in,
                              void* d_out, int out_size, void* d_ws, size_t ws_size,
                              hipStream_t stream) {
  const float* x = (const float*)d_in[0];
  const float* w_ih = (const float*)d_in[1];
  const float* w_hh = (const float*)d_in[2];
  const float* b_ih = (const float*)d_in[3];
  const float* b_hh = (const float*)d_in[4];
  const float* fc_w = (const float*)d_in[5];
  const float* fc_b = (const float*)d_in[6];

  init_flags<<<1, 256, 0, stream>>>();
  gru_persistent<<<NCL * NWG, 256, 0, stream>>>(x, w_ih, w_hh, b_ih, b_hh,
                                                fc_w, fc_b, (float*)d_out);
}

// Round 16
// 1899.803 us; speedup vs baseline: 1.7120x; 1.7120x over previous
//
#include <hip/hip_runtime.h>
#include <hip/hip_bf16.h>

#define B_ 256
#define T_ 512
#define F_ 8
#define H_ 512
#define OUT_ 96

// 16 batch-clusters x (4 workgroups x 8 waves). Each wave owns 16 h-cols
// (48 gate-cols), W slice register-resident (208 VGPR = exactly 8 waves/CU ->
// 1 wg/CU). 64 blocks of 512 thr => co-residency guaranteed by capacity.
// r8 exchange protocol (best, 1722us) with HALF the producers: tail of
// max-of-4 flags instead of max-of-8, half the flag/publish bursts.
#define NCL 16
#define BT 16
#define NWG 4

typedef __attribute__((ext_vector_type(8))) short short8;
typedef __attribute__((ext_vector_type(4))) float f32x4;

// g_hbuf: [buf][chunk=col>>3][row][2 u64]  (16B = 8 bf16 cols per (chunk,row))
__device__ unsigned long long g_hbuf[2ull * 64 * 256 * 2];
// per-cluster flag block: 4 u32 packed in ONE 64B line (single-request poll)
__device__ __align__(64) unsigned g_flag[NCL * 16];

__device__ __forceinline__ short f2bf(float v) {
  __hip_bfloat16 b = __float2bfloat16(v);
  unsigned short u;
  __builtin_memcpy(&u, &b, 2);
  return (short)u;
}

__device__ __forceinline__ size_t hidx(int buf, int chunk, int row) {
  return ((size_t)((buf * 64 + chunk) * 256 + row)) * 2;
}

__global__ void init_flags() {
  int i = blockIdx.x * 256 + (int)threadIdx.x;
  if (i < NCL * 16) g_flag[i] = 0;
}

__global__ __launch_bounds__(512, 1) void gru_persistent(
    const float* x, const float* w_ih, const float* w_hh,
    const float* bias_ih, const float* bias_hh,
    const float* fc_w, const float* fc_b, float* out) {
  const int tid = (int)threadIdx.x;
  const int w = tid >> 6;          // wave 0..7
  const int lane = tid & 63;
  const int l15 = lane & 15;
  const int lg = lane >> 4;
  const int bid = (int)blockIdx.x;
  const int cl = bid & 15;   // cluster
  const int wgj = bid >> 4;  // wg within cluster (0..3)
  const int rb0 = cl * BT;
  const int c0 = wgj * 128 + w * 16;

  __shared__ short8 h_lds[1024];   // [chunk*16 + localrow], lane-linear (16 KB)
  __shared__ short t_h[16][136];   // publish transpose tile (272B rows, 8B-mult)

  // ---- W fragments, register-resident for all 512 steps ----
  short8 wfrag[3][17];
#pragma unroll
  for (int g = 0; g < 3; ++g) {
    const float* wr = w_hh + (size_t)(g * H_ + c0 + l15) * H_ + lg * 8;
#pragma unroll
    for (int kk = 0; kk < 16; ++kk) {
      f32x4 a = ((const f32x4*)(wr + kk * 32))[0];
      f32x4 b2 = ((const f32x4*)(wr + kk * 32))[1];
      short8 o;
#pragma unroll
      for (int j = 0; j < 4; ++j) { o[j] = f2bf(a[j]); o[4 + j] = f2bf(b2[j]); }
      wfrag[g][kk] = o;
    }
    short8 o = {0, 0, 0, 0, 0, 0, 0, 0};
    if (lg == 0) {  // k = 512..519 -> W_ih row
      const f32x4* wi = (const f32x4*)(w_ih + (size_t)(g * H_ + c0 + l15) * F_);
      f32x4 a = wi[0], b2 = wi[1];
#pragma unroll
      for (int j = 0; j < 4; ++j) { o[j] = f2bf(a[j]); o[4 + j] = f2bf(b2[j]); }
    }
    wfrag[g][16] = o;
  }

  const int colh = c0 + l15;
  const float b_r = bias_ih[colh] + bias_hh[colh];
  const float b_z = bias_ih[H_ + colh] + bias_hh[H_ + colh];
  const float bin_ = bias_ih[2 * H_ + colh];
  const float bhn_ = bias_hh[2 * H_ + colh];

  float hown[4] = {0.f, 0.f, 0.f, 0.f};
  bool gaveup = false;

  const int hrow = rb0 + l15;
  const float* xrow = x + (size_t)hrow * T_ * F_;

  // x prefetch for t=0
  f32x4 xa = ((const f32x4*)xrow)[0];
  f32x4 xb2 = ((const f32x4*)xrow)[1];

  for (int t = 0; t < T_; ++t) {
    // ---- x fragment + hoisted x-MFMAs (independent of the gather/poll) ----
    short8 xf;
#pragma unroll
    for (int j = 0; j < 4; ++j) { xf[j] = f2bf(xa[j]); xf[4 + j] = f2bf(xb2[j]); }
    f32x4 acc_r = {0.f, 0.f, 0.f, 0.f}, acc_z = {0.f, 0.f, 0.f, 0.f};
    f32x4 acc_nh = {0.f, 0.f, 0.f, 0.f}, acc_nx = {0.f, 0.f, 0.f, 0.f};
    acc_r = __builtin_amdgcn_mfma_f32_16x16x32_bf16(xf, wfrag[0][16], acc_r, 0, 0, 0);
    acc_z = __builtin_amdgcn_mfma_f32_16x16x32_bf16(xf, wfrag[1][16], acc_z, 0, 0, 0);
    acc_nx = __builtin_amdgcn_mfma_f32_16x16x32_bf16(xf, wfrag[2][16], acc_nx, 0, 0, 0);

    if (t > 0) {
      // ---- poll: ONE coalesced line-load per wave per iteration, __all exit ----
      if (!gaveup) {
        unsigned spins = 0;
        for (;;) {
          unsigned f = __hip_atomic_load(&g_flag[cl * 16 + (lane & 3)],
                                         __ATOMIC_RELAXED, __HIP_MEMORY_SCOPE_AGENT);
          if (__all((int)(f >= (unsigned)t))) break;
          __builtin_amdgcn_s_sleep(1);
          if (++spins > (1u << 20)) { gaveup = true; break; }
        }
        __builtin_amdgcn_sched_barrier(0);  // gathers issue only after poll exit
      }
      // ---- cooperative gather (atomic u64, proven): lane-linear LDS writes ----
      const int buf = t & 1;
#pragma unroll
      for (int r4 = 0; r4 < 2; ++r4) {
        const int idx = r4 * 512 + tid;     // 0..1023
        size_t i0 = hidx(buf, idx >> 4, rb0 + (idx & 15));
        unsigned long long q0 = __hip_atomic_load(&g_hbuf[i0], __ATOMIC_RELAXED,
                                                  __HIP_MEMORY_SCOPE_AGENT);
        unsigned long long q1 = __hip_atomic_load(&g_hbuf[i0 + 1], __ATOMIC_RELAXED,
                                                  __HIP_MEMORY_SCOPE_AGENT);
        union { unsigned long long q[2]; short8 s; } u;
        u.q[0] = q0; u.q[1] = q1;
        h_lds[idx] = u.s;
      }
    }

    __syncthreads();  // h_lds ready

    // prefetch x for t+1 (overlaps MFMA)
    {
      const int tn = (t + 1 < T_) ? t + 1 : T_ - 1;
      xa = ((const f32x4*)(xrow + (size_t)tn * F_))[0];
      xb2 = ((const f32x4*)(xrow + (size_t)tn * F_))[1];
    }

    // ---- h MFMAs: 3 gates per kk ----
    if (t > 0) {
#pragma unroll
      for (int kk = 0; kk < 16; ++kk) {
        short8 a = h_lds[(kk * 4 + lg) * 16 + l15];
        acc_r = __builtin_amdgcn_mfma_f32_16x16x32_bf16(a, wfrag[0][kk], acc_r, 0, 0, 0);
        acc_z = __builtin_amdgcn_mfma_f32_16x16x32_bf16(a, wfrag[1][kk], acc_z, 0, 0, 0);
        acc_nh = __builtin_amdgcn_mfma_f32_16x16x32_bf16(a, wfrag[2][kk], acc_nh, 0, 0, 0);
      }
    }

    // ---- gates + fp32-carry state update ----
    short hnew[4];
#pragma unroll
    for (int q = 0; q < 4; ++q) {
      float pr = acc_r[q] + b_r;
      float pz = acc_z[q] + b_z;
      float r = 1.f / (1.f + __expf(-pr));
      float z = 1.f / (1.f + __expf(-pz));
      float n = tanhf(acc_nx[q] + bin_ + r * (acc_nh[q] + bhn_));
      hown[q] = n + z * (hown[q] - n);
      hnew[q] = f2bf(hown[q]);
    }

    // ---- publish via padded LDS transpose -> one aligned u64 atomic store/lane ----
#pragma unroll
    for (int q = 0; q < 4; ++q) t_h[4 * lg + q][w * 16 + l15] = hnew[q];
    __syncthreads();  // tile complete
    {
      const int row_l = tid >> 5;       // 0..15
      const int ucol = tid & 31;        // 0..31 -> 4 cols each
      const int col = wgj * 128 + ucol * 4;
      const int grow = rb0 + row_l;
      unsigned long long v;
      __builtin_memcpy(&v, &t_h[row_l][ucol * 4], 8);
      size_t i0 = hidx((t + 1) & 1, col >> 3, grow) + ((col >> 2) & 1);
      __hip_atomic_store(&g_hbuf[i0], v, __ATOMIC_RELAXED, __HIP_MEMORY_SCOPE_AGENT);
    }
    __syncthreads();  // vmcnt(0) drain: all 8 waves' stores at coherence point
    if (tid == 0)     // release: relaxed store into the packed cluster line
      __hip_atomic_store(&g_flag[cl * 16 + wgj], (unsigned)(t + 1),
                         __ATOMIC_RELAXED, __HIP_MEMORY_SCOPE_AGENT);
  }

  // ---- final FC: 6 waves (wg 0) cover the 96 output columns ----
  const int wi = wgj * 8 + w;
  if (wi >= OUT_ / 16) return;
  if (!gaveup) {
    unsigned spins = 0;
    for (;;) {
      unsigned f = __hip_atomic_load(&g_flag[cl * 16 + (lane & 3)],
                                     __ATOMIC_RELAXED, __HIP_MEMORY_SCOPE_AGENT);
      if (__all((int)(f >= (unsigned)T_))) break;
      __builtin_amdgcn_s_sleep(1);
      if (++spins > (1u << 20)) break;
    }
    __builtin_amdgcn_fence(__ATOMIC_ACQUIRE, "agent");  // once, cheap
  }
  short8 afrag[16];
#pragma unroll
  for (int kk = 0; kk < 16; ++kk) {  // h_512 is in buffer (512 & 1) == 0
    size_t i0 = hidx(0, kk * 4 + lg, hrow);
    unsigned long long q0 =
        __hip_atomic_load(&g_hbuf[i0], __ATOMIC_RELAXED, __HIP_MEMORY_SCOPE_AGENT);
    unsigned long long q1 =
        __hip_atomic_load(&g_hbuf[i0 + 1], __ATOMIC_RELAXED, __HIP_MEMORY_SCOPE_AGENT);
    union { unsigned long long q[2]; short8 s; } u;
    u.q[0] = q0; u.q[1] = q1;
    afrag[kk] = u.s;
  }
  const int col = wi * 16 + l15;
  const float* wrow = fc_w + (size_t)col * H_ + lg * 8;
  f32x4 acc = {0.f, 0.f, 0.f, 0.f};
#pragma unroll
  for (int kk = 0; kk < 16; ++kk) {
    f32x4 a = ((const f32x4*)(wrow + kk * 32))[0];
    f32x4 b2 = ((const f32x4*)(wrow + kk * 32))[1];
    short8 bfr;
#pragma unroll
    for (int j = 0; j < 4; ++j) { bfr[j] = f2bf(a[j]); bfr[4 + j] = f2bf(b2[j]); }
    acc = __builtin_amdgcn_mfma_f32_16x16x32_bf16(afrag[kk], bfr, acc, 0, 0, 0);
  }
  const float fb = fc_b[col];
#pragma unroll
  for (int q = 0; q < 4; ++q) {
    int row_o = rb0 + lg * 4 + q;
    out[(size_t)row_o * OUT_ + col] = acc[q] + fb;
  }
}

extern "C" void kernel_launch(void* const* d_in, const int* in_sizes, int n_in,
                              void* d_out, int out_size, void* d_ws, size_t ws_size,
                              hipStream_t stream) {
  const float* x = (const float*)d_in[0];
  const float* w_ih = (const float*)d_in[1];
  const float* w_hh = (const float*)d_in[2];
  const float* b_ih = (const float*)d_in[3];
  const float* b_hh = (const float*)d_in[4];
  const float* fc_w = (const float*)d_in[5];
  const float* fc_b = (const float*)d_in[6];

  init_flags<<<1, 256, 0, stream>>>();
  gru_persistent<<<NCL * NWG, 512, 0, stream>>>(x, w_ih, w_hh, b_ih, b_hh,
                                                fc_w, fc_b, (float*)d_out);
}